// Round 5
// baseline (240.549 us; speedup 1.0000x reference)
//
#include <hip/hip_runtime.h>
#include <hip/hip_cooperative_groups.h>

namespace cg = cooperative_groups;

// Problem constants (from reference)
#define BATCH 2048
#define FDIM  1024
#define GTILE 16
#define F4    (FDIM / 4)          // 256 float4 column-groups
#define NBLK  256                 // stats blocks; == F4 so block b owns group b
#define ROWS  (BATCH / NBLK)      // 8 rows per block per pass

// ws layout (in floats):
#define OFF_P1   0                // [NBLK][FDIM] partial col sums of xf
#define OFF_P2S  262144           // [NBLK][FDIM] partial col sums of relu(xf-mean)
#define OFF_P2Q  524288           // [NBLK][FDIM] partial col sumsq
#define OFF_MEAN 786432           // [FDIM]
#define OFF_SC   787456           // [FDIM] scale = wp/sd
#define OFF_CC   788480           // [FDIM] mu*scale

__device__ __forceinline__ void v4add(float4& a, const float4& b) {
    a.x += b.x; a.y += b.y; a.z += b.z; a.w += b.w;
}

// One cooperative dispatch: P1 col-sums -> sync -> P2 mean -> sync ->
// P3 relu stats -> sync -> P4 finalize (sc, cc).
__global__ void __launch_bounds__(256) kstats(const float4* __restrict__ xf,
                                              const float* __restrict__ wp,
                                              float4* __restrict__ p1,
                                              float4* __restrict__ p2s,
                                              float4* __restrict__ p2q,
                                              float4* __restrict__ mean,
                                              float4* __restrict__ sc,
                                              float4* __restrict__ cc) {
    cg::grid_group grid = cg::this_grid();
    const int tid = threadIdx.x;   // 0..255 -> column group
    const int b   = blockIdx.x;    // 0..255 -> row chunk (P1/P3) / column group (P2/P4)
    __shared__ float4 redA[256];   // 4 KB
    __shared__ float4 redB[256];   // 4 KB

    // ---- P1: partial column sums of xf over this block's 8 rows ----
    {
        const float4* p = xf + (size_t)b * ROWS * F4 + tid;
        float4 s = {0.f, 0.f, 0.f, 0.f};
#pragma unroll
        for (int r = 0; r < ROWS; ++r) v4add(s, p[r * F4]);
        p1[b * F4 + tid] = s;
    }
    grid.sync();

    // ---- P2: block b reduces chunk-partials for column group b -> mean ----
    {
        redA[tid] = p1[tid * F4 + b];
        __syncthreads();
        for (int off = 128; off > 0; off >>= 1) {
            if (tid < off) v4add(redA[tid], redA[tid + off]);
            __syncthreads();
        }
        if (tid == 0) {
            const float inv_n = 1.0f / (float)BATCH;
            float4 m = redA[0];
            m.x *= inv_n; m.y *= inv_n; m.z *= inv_n; m.w *= inv_n;
            mean[b] = m;
        }
    }
    grid.sync();

    // ---- P3: relu(x - mean) partial sums & sumsq over this block's rows ----
    {
        float4 m = mean[tid];
        const float4* p = xf + (size_t)b * ROWS * F4 + tid;
        float4 s = {0.f, 0.f, 0.f, 0.f};
        float4 q = {0.f, 0.f, 0.f, 0.f};
#pragma unroll
        for (int r = 0; r < ROWS; ++r) {
            float4 v = p[r * F4];
            float rx = fmaxf(v.x - m.x, 0.f);
            float ry = fmaxf(v.y - m.y, 0.f);
            float rz = fmaxf(v.z - m.z, 0.f);
            float rw = fmaxf(v.w - m.w, 0.f);
            s.x += rx; s.y += ry; s.z += rz; s.w += rw;
            q.x += rx * rx; q.y += ry * ry; q.z += rz * rz; q.w += rw * rw;
        }
        p2s[b * F4 + tid] = s;
        p2q[b * F4 + tid] = q;
    }
    grid.sync();

    // ---- P4: block b reduces s,q for column group b -> sc, cc ----
    {
        redA[tid] = p2s[tid * F4 + b];
        redB[tid] = p2q[tid * F4 + b];
        __syncthreads();
        for (int off = 128; off > 0; off >>= 1) {
            if (tid < off) { v4add(redA[tid], redA[tid + off]); v4add(redB[tid], redB[tid + off]); }
            __syncthreads();
        }
        if (tid == 0) {
            const float inv_n = 1.0f / (float)BATCH;
            const float w = wp[0];
            float4 S = redA[0], Q = redB[0];
            float4 scale, cmb;
            float mu, var;
            mu = S.x * inv_n; var = (Q.x - S.x * mu) / (float)(BATCH - 1);
            scale.x = w * rsqrtf(var); cmb.x = mu * scale.x;
            mu = S.y * inv_n; var = (Q.y - S.y * mu) / (float)(BATCH - 1);
            scale.y = w * rsqrtf(var); cmb.y = mu * scale.y;
            mu = S.z * inv_n; var = (Q.z - S.z * mu) / (float)(BATCH - 1);
            scale.z = w * rsqrtf(var); cmb.z = mu * scale.z;
            mu = S.w * inv_n; var = (Q.w - S.w * mu) / (float)(BATCH - 1);
            scale.w = w * rsqrtf(var); cmb.w = mu * scale.w;
            sc[b] = scale;
            cc[b] = cmb;
        }
    }
}

__global__ void k4_write(const float4* __restrict__ xf,
                         const float4* __restrict__ mean,
                         const float4* __restrict__ sc,
                         const float4* __restrict__ cc,
                         float4* __restrict__ out) {
    const int tid = threadIdx.x;     // 0..255
    const int row = blockIdx.x;      // 0..2047
    float4 m = mean[tid];
    float4 a = sc[tid];
    float4 c = cc[tid];
    float4 v = xf[(size_t)row * F4 + tid];
    float4 o;
    o.x = fmaxf(v.x - m.x, 0.f) * a.x - c.x;
    o.y = fmaxf(v.y - m.y, 0.f) * a.y - c.y;
    o.z = fmaxf(v.z - m.z, 0.f) * a.z - c.z;
    o.w = fmaxf(v.w - m.w, 0.f) * a.w - c.w;
    float4* dst = out + (size_t)row * (GTILE * F4) + tid;
#pragma unroll
    for (int g = 0; g < GTILE; ++g) {
        dst[g * F4] = o;
    }
}

extern "C" void kernel_launch(void* const* d_in, const int* in_sizes, int n_in,
                              void* d_out, int out_size, void* d_ws, size_t ws_size,
                              hipStream_t stream) {
    const float4* xf4 = (const float4*)d_in[0];
    const float* wp = (const float*)d_in[1];
    float* ws = (float*)d_ws;
    float4* out = (float4*)d_out;

    float4* p1   = (float4*)(ws + OFF_P1);
    float4* p2s  = (float4*)(ws + OFF_P2S);
    float4* p2q  = (float4*)(ws + OFF_P2Q);
    float4* mean = (float4*)(ws + OFF_MEAN);
    float4* sc   = (float4*)(ws + OFF_SC);
    float4* cc   = (float4*)(ws + OFF_CC);

    void* args[] = { (void*)&xf4, (void*)&wp, (void*)&p1, (void*)&p2s,
                     (void*)&p2q, (void*)&mean, (void*)&sc, (void*)&cc };
    hipLaunchCooperativeKernel((const void*)kstats, dim3(NBLK), dim3(256),
                               args, 0, stream);
    k4_write<<<BATCH, 256, 0, stream>>>(xf4, mean, sc, cc, out);
}

// Round 6
// 155.144 us; speedup vs baseline: 1.5505x; 1.5505x over previous
//
#include <hip/hip_runtime.h>

// Problem constants (from reference)
#define BATCH 2048
#define FDIM  1024
#define GTILE 16
#define F4    (FDIM / 4)                  // 256 float4 col-groups per row
#define CHUNKS 128
#define ROWS_PER_CHUNK (BATCH / CHUNKS)   // 16

// ws layout (in floats):
#define OFF_P1   0                        // [CHUNKS][FDIM] partial col sums of xf
#define OFF_P2S  131072                   // [CHUNKS][FDIM] partial col sums of relu(xf-mean)
#define OFF_P2Q  262144                   // [CHUNKS][FDIM] partial col sumsq
#define OFF_MEAN 393216                   // [FDIM]
#define OFF_SC   394240                   // [FDIM] scale = wp/sd
#define OFF_CC   395264                   // [FDIM] mu*scale

__device__ __forceinline__ void v4add(float4& a, const float4& b) {
    a.x += b.x; a.y += b.y; a.z += b.z; a.w += b.w;
}

__global__ void k1_partial_sum(const float4* __restrict__ xf, float4* __restrict__ p1) {
    const int tid = threadIdx.x;            // 0..255 -> 4 columns each
    const int chunk = blockIdx.x;           // 0..127
    const float4* p = xf + (size_t)chunk * ROWS_PER_CHUNK * F4 + tid;
    float4 s = {0.f, 0.f, 0.f, 0.f};
#pragma unroll
    for (int r = 0; r < ROWS_PER_CHUNK; ++r) v4add(s, p[r * F4]);
    p1[chunk * F4 + tid] = s;
}

__global__ void k2_relu_partial(const float4* __restrict__ xf,
                                const float4* __restrict__ p1,
                                float4* __restrict__ p2s,
                                float4* __restrict__ p2q) {
    const int tid = threadIdx.x;
    const int chunk = blockIdx.x;
    // Redundantly reduce p1 -> per-column mean (L2-cached, coalesced).
    float4 m = {0.f, 0.f, 0.f, 0.f};
#pragma unroll 8
    for (int c = 0; c < CHUNKS; ++c) v4add(m, p1[c * F4 + tid]);
    const float inv_n = 1.0f / (float)BATCH;
    m.x *= inv_n; m.y *= inv_n; m.z *= inv_n; m.w *= inv_n;

    const float4* p = xf + (size_t)chunk * ROWS_PER_CHUNK * F4 + tid;
    float4 s = {0.f, 0.f, 0.f, 0.f};
    float4 q = {0.f, 0.f, 0.f, 0.f};
#pragma unroll
    for (int r = 0; r < ROWS_PER_CHUNK; ++r) {
        float4 v = p[r * F4];
        float rx = fmaxf(v.x - m.x, 0.f);
        float ry = fmaxf(v.y - m.y, 0.f);
        float rz = fmaxf(v.z - m.z, 0.f);
        float rw = fmaxf(v.w - m.w, 0.f);
        s.x += rx; s.y += ry; s.z += rz; s.w += rw;
        q.x += rx * rx; q.y += ry * ry; q.z += rz * rz; q.w += rw * rw;
    }
    p2s[chunk * F4 + tid] = s;
    p2q[chunk * F4 + tid] = q;
}

// 16 blocks x 256 threads. Block b owns col-groups [b*16, b*16+16).
// Thread t: cg = b*16 + (t&15), slice = t>>4 -> 8 chunks. Coalesced loads,
// LDS tree over the 16 slices.
__global__ void k3_finalize(const float* __restrict__ wp,
                            const float4* __restrict__ p1,
                            const float4* __restrict__ p2s,
                            const float4* __restrict__ p2q,
                            float4* __restrict__ mean,
                            float4* __restrict__ sc,
                            float4* __restrict__ cc) {
    __shared__ float4 rm[256], rs[256], rq[256];   // 12 KB
    const int t = threadIdx.x;
    const int b = blockIdx.x;                      // 0..15
    const int cg = b * 16 + (t & 15);              // col-group
    const int slice = t >> 4;                      // 0..15
    const int c0 = slice * (CHUNKS / 16);          // 8 chunks per slice
    float4 m = {0.f,0.f,0.f,0.f}, s = {0.f,0.f,0.f,0.f}, q = {0.f,0.f,0.f,0.f};
#pragma unroll
    for (int c = c0; c < c0 + CHUNKS / 16; ++c) {
        v4add(m, p1[c * F4 + cg]);
        v4add(s, p2s[c * F4 + cg]);
        v4add(q, p2q[c * F4 + cg]);
    }
    rm[t] = m; rs[t] = s; rq[t] = q;
    __syncthreads();
    for (int off = 128; off >= 16; off >>= 1) {
        if (t < off) { v4add(rm[t], rm[t + off]); v4add(rs[t], rs[t + off]); v4add(rq[t], rq[t + off]); }
        __syncthreads();
    }
    if (t < 16) {
        const float inv_n = 1.0f / (float)BATCH;
        const float w = wp[0];
        float4 M = rm[t], S = rs[t], Q = rq[t];
        float4 mn, scale, cmb;
        float mu, var;
        mn.x = M.x * inv_n;
        mu = S.x * inv_n; var = (Q.x - S.x * mu) / (float)(BATCH - 1);
        scale.x = w * rsqrtf(var); cmb.x = mu * scale.x;
        mn.y = M.y * inv_n;
        mu = S.y * inv_n; var = (Q.y - S.y * mu) / (float)(BATCH - 1);
        scale.y = w * rsqrtf(var); cmb.y = mu * scale.y;
        mn.z = M.z * inv_n;
        mu = S.z * inv_n; var = (Q.z - S.z * mu) / (float)(BATCH - 1);
        scale.z = w * rsqrtf(var); cmb.z = mu * scale.z;
        mn.w = M.w * inv_n;
        mu = S.w * inv_n; var = (Q.w - S.w * mu) / (float)(BATCH - 1);
        scale.w = w * rsqrtf(var); cmb.w = mu * scale.w;
        mean[b * 16 + t] = mn;
        sc[b * 16 + t]   = scale;
        cc[b * 16 + t]   = cmb;
    }
}

__global__ void k4_write(const float4* __restrict__ xf,
                         const float4* __restrict__ mean,
                         const float4* __restrict__ sc,
                         const float4* __restrict__ cc,
                         float4* __restrict__ out) {
    const int tid = threadIdx.x;     // 0..255
    const int row = blockIdx.x;      // 0..2047
    float4 m = mean[tid];
    float4 a = sc[tid];
    float4 c = cc[tid];
    float4 v = xf[(size_t)row * F4 + tid];
    float4 o;
    o.x = fmaxf(v.x - m.x, 0.f) * a.x - c.x;
    o.y = fmaxf(v.y - m.y, 0.f) * a.y - c.y;
    o.z = fmaxf(v.z - m.z, 0.f) * a.z - c.z;
    o.w = fmaxf(v.w - m.w, 0.f) * a.w - c.w;
    float4* dst = out + (size_t)row * (GTILE * F4) + tid;
#pragma unroll
    for (int g = 0; g < GTILE; ++g) {
        dst[g * F4] = o;
    }
}

extern "C" void kernel_launch(void* const* d_in, const int* in_sizes, int n_in,
                              void* d_out, int out_size, void* d_ws, size_t ws_size,
                              hipStream_t stream) {
    const float4* xf4 = (const float4*)d_in[0];
    const float* wp = (const float*)d_in[1];
    float* ws = (float*)d_ws;
    float4* out = (float4*)d_out;

    float4* p1   = (float4*)(ws + OFF_P1);
    float4* p2s  = (float4*)(ws + OFF_P2S);
    float4* p2q  = (float4*)(ws + OFF_P2Q);
    float4* mean = (float4*)(ws + OFF_MEAN);
    float4* sc   = (float4*)(ws + OFF_SC);
    float4* cc   = (float4*)(ws + OFF_CC);

    k1_partial_sum<<<CHUNKS, 256, 0, stream>>>(xf4, p1);
    k2_relu_partial<<<CHUNKS, 256, 0, stream>>>(xf4, p1, p2s, p2q);
    k3_finalize<<<16, 256, 0, stream>>>(wp, p1, p2s, p2q, mean, sc, cc);
    k4_write<<<BATCH, 256, 0, stream>>>(xf4, mean, sc, cc, out);
}